// Round 3
// baseline (360.548 us; speedup 1.0000x reference)
//
#include <hip/hip_runtime.h>

#define NB 1024
#define NV 6890
#define NJ 24
#define NBETA 10
#define NPOSE 207
#define NK 19
#define NKJ 456       // 19*24
#define NCOL 1368     // 3*456
#define KR 218        // coef rows: 207 pose + 10 beta + 1 const
#define AR 219        // GEMM A rows: KR + s-row
#define VSTR 20670    // 3*NV

// workspace layout (floats)
#define OFF_OUT  0ull
#define SZ_OUT   ((size_t)AR*NCOL)           // 299,592
#define OFF_COEF (OFF_OUT + SZ_OUT)
#define SZ_COEF  ((size_t)KR*NB)             // 223,232
#define OFF_AW   (OFF_COEF + SZ_COEF)
#define SZ_AW    ((size_t)NB*288)            // 294,912
#define OFF_JS   (OFF_AW + SZ_AW)
#define SZ_JS    (11ull*24*3)                // 792
#define OFF_M    (OFF_JS + SZ_JS)
#define SZ_M     ((size_t)NB*NCOL)           // 1,400,832
// total ~8.9 MB

// JS[row<10][j][a] = sum_v Jreg[v,j]*shapedirs[row,3v+a];  JS[10][j][a] = sum_v Jreg[v,j]*vt[v,a]
__global__ void k_js(const float* __restrict__ Jreg, const float* __restrict__ sd,
                     const float* __restrict__ vt, float* __restrict__ JS) {
    int row = blockIdx.x / NJ;
    int j = blockIdx.x - row * NJ;
    int lane = threadIdx.x;
    const float* src = (row < NBETA) ? (sd + (size_t)row * VSTR) : vt;
    float a0 = 0.f, a1 = 0.f, a2 = 0.f;
    for (int v = lane; v < NV; v += 64) {
        float jrv = Jreg[v * NJ + j];
        a0 += jrv * src[3 * v];
        a1 += jrv * src[3 * v + 1];
        a2 += jrv * src[3 * v + 2];
    }
    for (int off = 32; off; off >>= 1) {
        a0 += __shfl_down(a0, off);
        a1 += __shfl_down(a1, off);
        a2 += __shfl_down(a2, off);
    }
    if (lane == 0) {
        JS[(row * NJ + j) * 3 + 0] = a0;
        JS[(row * NJ + j) * 3 + 1] = a1;
        JS[(row * NJ + j) * 3 + 2] = a2;
    }
}

// per-batch: Rodrigues, pose_feature -> coefT, joint locations, kinematic chain -> A (rot+trans)
__global__ __launch_bounds__(64) void k_pose(const float* __restrict__ beta,
                                             const float* __restrict__ theta,
                                             const float* __restrict__ JS,
                                             float* __restrict__ coefT,
                                             float* __restrict__ Aw) {
    int n = blockIdx.x;
    int tid = threadIdx.x;
    __shared__ float Rs[24][9];
    __shared__ float Jl[24][3];
    __shared__ float G[24][12];

    if (tid < NJ) {
        int j = tid;
        float x = theta[n * 72 + j * 3 + 0];
        float y = theta[n * 72 + j * 3 + 1];
        float z = theta[n * 72 + j * 3 + 2];
        float ang = sqrtf(x * x + y * y + z * z + 1e-8f);
        float inv = 1.0f / ang;
        float rx = x * inv, ry = y * inv, rz = z * inv;
        float ct = cosf(ang), st = sinf(ang), oc = 1.0f - ct;
        float R[9];
        R[0] = ct + oc * rx * rx;  R[1] = -st * rz + oc * rx * ry; R[2] =  st * ry + oc * rx * rz;
        R[3] =  st * rz + oc * ry * rx; R[4] = ct + oc * ry * ry;  R[5] = -st * rx + oc * ry * rz;
        R[6] = -st * ry + oc * rz * rx; R[7] =  st * rx + oc * rz * ry; R[8] = ct + oc * rz * rz;
#pragma unroll
        for (int e = 0; e < 9; e++) Rs[j][e] = R[e];
        if (j >= 1) {
#pragma unroll
            for (int e = 0; e < 9; e++)
                coefT[(size_t)((j - 1) * 9 + e) * NB + n] =
                    R[e] - ((e == 0 || e == 4 || e == 8) ? 1.0f : 0.0f);
        }
    }
    if (tid < NBETA) coefT[(size_t)(NPOSE + tid) * NB + n] = beta[n * NBETA + tid];
    if (tid == 63)   coefT[(size_t)217 * NB + n] = 1.0f;
    __syncthreads();

    for (int idx = tid; idx < 72; idx += 64) {
        int j = idx / 3, a = idx - j * 3;
        float acc = JS[(NBETA * NJ + j) * 3 + a];
#pragma unroll
        for (int b = 0; b < NBETA; b++) acc += beta[n * NBETA + b] * JS[(b * NJ + j) * 3 + a];
        Jl[j][a] = acc;
    }
    __syncthreads();

    if (tid < 12) {
        int r = tid >> 2, cc = tid & 3;
        G[0][tid] = (cc < 3) ? Rs[0][r * 3 + cc] : Jl[0][r];
    }
    __syncthreads();

    const int PAR[24] = {0,0,0,0,1,2,3,4,5,6,7,8,9,9,9,12,13,14,16,17,18,19,20,21};
#pragma unroll
    for (int i = 1; i < NJ; i++) {
        int p = PAR[i];
        if (tid < 12) {
            int r = tid >> 2, cc = tid & 3;
            float g0 = G[p][r * 4 + 0], g1 = G[p][r * 4 + 1];
            float g2 = G[p][r * 4 + 2], g3 = G[p][r * 4 + 3];
            float val;
            if (cc < 3) {
                val = g0 * Rs[i][cc] + g1 * Rs[i][3 + cc] + g2 * Rs[i][6 + cc];
            } else {
                float t0 = Jl[i][0] - Jl[p][0];
                float t1 = Jl[i][1] - Jl[p][1];
                float t2 = Jl[i][2] - Jl[p][2];
                val = g0 * t0 + g1 * t1 + g2 * t2 + g3;
            }
            G[i][tid] = val;
        }
        __syncthreads();
    }

    for (int idx = tid; idx < 288; idx += 64) {
        int j = idx / 12, e = idx - j * 12;
        float val;
        if (e < 9) {
            int r = e / 3, cc = e - 3 * (e / 3);
            val = G[j][r * 4 + cc];
        } else {
            int r = e - 9;
            val = G[j][r * 4 + 3] -
                  (G[j][r * 4 + 0] * Jl[j][0] + G[j][r * 4 + 1] * Jl[j][1] +
                   G[j][r * 4 + 2] * Jl[j][2]);
        }
        Aw[(size_t)n * 288 + idx] = val;
    }
}

// OUT[r][a*456+col] += sum_v A[r][v;a] * jr[v,k]*w[v,j]
// A rows: {posedirs, shapedirs, v_template, ones}; staged directly from inputs (no AT/cw temps).
__global__ __launch_bounds__(256) void k_gemmP(const float* __restrict__ pd,
                                               const float* __restrict__ sd,
                                               const float* __restrict__ vt,
                                               const float* __restrict__ jr,
                                               const float* __restrict__ w,
                                               float* __restrict__ OUTB) {
    int bid = blockIdx.x;
    int mt = bid & 3;  bid >>= 2;
    int nt = bid & 7;  bid >>= 3;
    int a = bid % 3;
    int ks = bid / 3;
    const int mb = mt * 64, nb = nt * 64;
    const int CH = 862;
    int v0 = ks * CH, v1 = min(NV, v0 + CH);
    __shared__ float As[32][64];   // [v][r], XOR-swizzled columns
    __shared__ float Bs[32][64];   // [v][col]
    int tid = threadIdx.x;
    int tm = tid & 15, tn = tid >> 4;

    int vlA = tid & 31;            // v lane for A staging
    int rrA = tid >> 5;            // 0..7 (r sub-row)
    int swA = (vlA & 15) << 2;     // XOR swizzle for this lane's LDS row

    int mB = tid & 63;             // col lane for B staging
    int kkB = tid >> 6;            // 0..3
    int colB = nb + mB;
    int kB = colB / NJ;
    int jB = colB - kB * NJ;
    bool okB = (colB < NKJ);

    float acc[4][4] = {};
    for (int vb = v0; vb < v1; vb += 32) {
        int vA = vb + vlA;
        bool okA = (vA < v1);
#pragma unroll
        for (int p = 0; p < 8; p++) {
            int m = rrA + p * 8;
            int r = mb + m;
            float val = 0.f;
            if (okA) {
                if (r < NPOSE)        val = pd[r * VSTR + 3 * vA + a];
                else if (r < 217)     val = sd[(r - NPOSE) * VSTR + 3 * vA + a];
                else if (r == 217)    val = vt[3 * vA + a];
                else if (r == 218)    val = 1.0f;
            }
            As[vlA][m ^ swA] = val;
        }
#pragma unroll
        for (int p = 0; p < 8; p++) {
            int kk = kkB + p * 4;
            int v = vb + kk;
            float val = 0.f;
            if (v < v1 && okB) val = jr[v * NK + kB] * w[v * NJ + jB];
            Bs[kk][mB] = val;
        }
        __syncthreads();
#pragma unroll
        for (int kk = 0; kk < 32; kk++) {
            float4 av = *(const float4*)&As[kk][(tm * 4) ^ ((kk & 15) << 2)];
            float4 bv = *(const float4*)&Bs[kk][tn * 4];
            float am[4] = {av.x, av.y, av.z, av.w};
            float bn[4] = {bv.x, bv.y, bv.z, bv.w};
#pragma unroll
            for (int i = 0; i < 4; i++)
#pragma unroll
                for (int j = 0; j < 4; j++) acc[i][j] += am[i] * bn[j];
        }
        __syncthreads();
    }
#pragma unroll
    for (int i = 0; i < 4; i++) {
        int r = mb + tm * 4 + i;
        if (r >= AR) continue;
#pragma unroll
        for (int j = 0; j < 4; j++) {
            int col = nb + tn * 4 + j;
            if (col < NKJ) atomicAdd(&OUTB[(size_t)r * NCOL + a * NKJ + col], acc[i][j]);
        }
    }
}

// M[n][col] = sum_r coefT[r][n] * OUT[r][col]   (1024 x 1368 x 218), 32x64 tiles for occupancy
__global__ __launch_bounds__(256) void k_gemmM(const float* __restrict__ coefT,
                                               const float* __restrict__ OUTB,
                                               float* __restrict__ M) {
    int bid = blockIdx.x;
    int mt = bid & 31, nt = bid >> 5;   // 32 x 22
    int mb = mt * 32, nb = nt * 64;
    __shared__ float Cs[32][32];
    __shared__ float Bs[32][64];
    int tid = threadIdx.x;
    int tm = tid & 15, tn = tid >> 4;
    float acc[2][4] = {};
    for (int kb = 0; kb < KR; kb += 32) {
#pragma unroll
        for (int p = 0; p < 4; p++) {
            int idx = tid + p * 256;
            int kk = idx >> 5, nl = idx & 31;
            int r = kb + kk;
            Cs[kk][nl] = (r < KR) ? coefT[(size_t)r * NB + mb + nl] : 0.f;
        }
#pragma unroll
        for (int p = 0; p < 8; p++) {
            int idx = tid + p * 256;
            int kk = idx >> 6, m = idx & 63;
            int r = kb + kk;
            int col = nb + m;
            Bs[kk][m] = (r < KR && col < NCOL) ? OUTB[(size_t)r * NCOL + col] : 0.f;
        }
        __syncthreads();
#pragma unroll
        for (int kk = 0; kk < 32; kk++) {
            float2 cv = *(const float2*)&Cs[kk][tm * 2];
            float4 bv = *(const float4*)&Bs[kk][tn * 4];
            float cm[2] = {cv.x, cv.y};
            float bn[4] = {bv.x, bv.y, bv.z, bv.w};
#pragma unroll
            for (int i = 0; i < 2; i++)
#pragma unroll
                for (int j = 0; j < 4; j++) acc[i][j] += cm[i] * bn[j];
        }
        __syncthreads();
    }
#pragma unroll
    for (int i = 0; i < 2; i++) {
        int n = mb + tm * 2 + i;
#pragma unroll
        for (int j = 0; j < 4; j++) {
            int col = nb + tn * 4 + j;
            if (col < NCOL) M[(size_t)n * NCOL + col] = acc[i][j];
        }
    }
}

// joints[n,k,a] = sum_j R_A[n,j,a,:].m[n,k,j,:] + s[k,j]*t_A[n,j,a]
__global__ void k_joints(const float* __restrict__ M, const float* __restrict__ Aw,
                         const float* __restrict__ OUTB, float* __restrict__ out) {
    int idx = blockIdx.x * 256 + threadIdx.x;
    if (idx >= NB * NK) return;
    int n = idx / NK, k = idx - n * NK;
    const float* A = Aw + (size_t)n * 288;
    const float* Mn = M + (size_t)n * NCOL;
    float o0 = 0.f, o1 = 0.f, o2 = 0.f;
#pragma unroll
    for (int j = 0; j < NJ; j++) {
        int kj = k * NJ + j;
        float m0 = Mn[kj];
        float m1 = Mn[NKJ + kj];
        float m2 = Mn[2 * NKJ + kj];
        float s = OUTB[(size_t)218 * NCOL + kj];
        const float* Aj = A + j * 12;
        o0 += Aj[0] * m0 + Aj[1] * m1 + Aj[2] * m2 + s * Aj[9];
        o1 += Aj[3] * m0 + Aj[4] * m1 + Aj[5] * m2 + s * Aj[10];
        o2 += Aj[6] * m0 + Aj[7] * m1 + Aj[8] * m2 + s * Aj[11];
    }
    out[idx * 3 + 0] = o0;
    out[idx * 3 + 1] = o1;
    out[idx * 3 + 2] = o2;
}

extern "C" void kernel_launch(void* const* d_in, const int* in_sizes, int n_in,
                              void* d_out, int out_size, void* d_ws, size_t ws_size,
                              hipStream_t stream) {
    const float* beta  = (const float*)d_in[0];
    const float* theta = (const float*)d_in[1];
    const float* vt    = (const float*)d_in[2];
    const float* sd    = (const float*)d_in[3];
    const float* Jreg  = (const float*)d_in[4];
    const float* pd    = (const float*)d_in[5];
    const float* w     = (const float*)d_in[6];
    const float* jr    = (const float*)d_in[7];

    float* ws    = (float*)d_ws;
    float* OUTB  = ws + OFF_OUT;
    float* coefT = ws + OFF_COEF;
    float* Aw    = ws + OFF_AW;
    float* JS    = ws + OFF_JS;
    float* M     = ws + OFF_M;
    float* out   = (float*)d_out;

    hipMemsetAsync(OUTB, 0, SZ_OUT * sizeof(float), stream);
    k_js<<<11 * NJ, 64, 0, stream>>>(Jreg, sd, vt, JS);
    k_pose<<<NB, 64, 0, stream>>>(beta, theta, JS, coefT, Aw);
    k_gemmP<<<4 * 8 * 3 * 8, 256, 0, stream>>>(pd, sd, vt, jr, w, OUTB);
    k_gemmM<<<32 * 22, 256, 0, stream>>>(coefT, OUTB, M);
    k_joints<<<(NB * NK + 255) / 256, 256, 0, stream>>>(M, Aw, OUTB, out);
}